// Round 1
// baseline (2393.391 us; speedup 1.0000x reference)
//
#include <hip/hip_runtime.h>

// CustomRNN: B=128, T=64, D=H=256, L=2, 3-node cell
//   n0 = tanh(x@Win + h@Wh0 + b0); n1 = relu(n0@Wh1 + b1) + n0;
//   n2 = sigmoid(n1@Wh2 + b2) + n0; h' = 0.5*(n1+n2)
// Strategy (round 1): batch-split, zero inter-WG sync. 8 WGs x 16 rows.
// fp16 MFMA (16x16x32), weights pre-transposed to [n][k] fp16 in ws.

typedef _Float16 f16;
typedef __attribute__((ext_vector_type(8))) _Float16 f16x8;
typedef __attribute__((ext_vector_type(4))) float f32x4;

#define Bb 128
#define Tt 64
#define Hh 256
#define APAD 264   // 264*2B = 528B row stride = 132 dwords; 132%32=4 -> 2-way LDS aliasing (free)

// ---------------- conversion kernels ----------------

__global__ void cvt_x_kernel(const float* __restrict__ x, f16* __restrict__ xh, int n) {
  int i = blockIdx.x * blockDim.x + threadIdx.x;
  int stride = gridDim.x * blockDim.x;
  for (; i < n; i += stride) xh[i] = (f16)x[i];
}

// Transpose each 256x256 matrix (row-major [k][n] f32) -> [n][k] fp16.
// 512 matrices total: 64 Win0 + 192 Wh0 + 64 Win1 + 192 Wh1.
__global__ void transpose_cvt_kernel(const float* __restrict__ Win0, const float* __restrict__ Wh0,
                                     const float* __restrict__ Win1, const float* __restrict__ Wh1,
                                     f16* __restrict__ Win0T, f16* __restrict__ Wh0T,
                                     f16* __restrict__ Win1T, f16* __restrict__ Wh1T) {
  __shared__ float tile[32][33];
  const int bid = blockIdx.x;
  const int mat = bid >> 6, tl = bid & 63;
  const int k0 = (tl & 7) << 5, n0 = (tl >> 3) << 5;
  const float* src; f16* dst;
  if (mat < 64)       { src = Win0 + (size_t)mat * 65536;        dst = Win0T + (size_t)mat * 65536; }
  else if (mat < 256) { src = Wh0  + (size_t)(mat - 64) * 65536; dst = Wh0T  + (size_t)(mat - 64) * 65536; }
  else if (mat < 320) { src = Win1 + (size_t)(mat - 256) * 65536; dst = Win1T + (size_t)(mat - 256) * 65536; }
  else                { src = Wh1  + (size_t)(mat - 320) * 65536; dst = Wh1T  + (size_t)(mat - 320) * 65536; }
  const int c = threadIdx.x & 31, r0 = threadIdx.x >> 5;
#pragma unroll
  for (int it = 0; it < 4; ++it) {
    const int r = r0 + it * 8;
    tile[r][c] = src[(k0 + r) * 256 + n0 + c];
  }
  __syncthreads();
#pragma unroll
  for (int it = 0; it < 4; ++it) {
    const int r = r0 + it * 8;
    dst[(size_t)(n0 + r) * 256 + k0 + c] = (f16)tile[c][r];   // dst[n][k] = src[k][n]
  }
}

// ---------------- RNN kernel ----------------
// MFMA f32_16x16x32_f16 layouts (per guide, HW-verified for this shape family):
//   A: lane holds A[m = lane&15][k = (lane>>4)*8 + j], j=0..7
//   B: lane holds B[k = (lane>>4)*8 + j][n = lane&15]  (we store W^T so these 8 k are contiguous)
//   C/D: reg r of lane holds D[row = (lane>>4)*4 + r][col = lane&15]

// Accumulate one K=256 matmul: A from LDS activation buffer row (padded), B = W^T from global.
__device__ __forceinline__ void mm_lds(f32x4 acc[2], const f16* abase,
                                       const f16* __restrict__ wt, int w, int q, int mn) {
#pragma unroll
  for (int kt = 0; kt < 8; ++kt) {
    const int k0 = kt * 32 + q * 8;
    f16x8 a = *(const f16x8*)(abase + k0);
#pragma unroll
    for (int nt = 0; nt < 2; ++nt) {
      f16x8 b = *(const f16x8*)(wt + (size_t)(w * 32 + nt * 16 + mn) * 256 + k0);
      acc[nt] = __builtin_amdgcn_mfma_f32_16x16x32_f16(a, b, acc[nt], 0, 0, 0);
    }
  }
}

// Same but A comes straight from global memory (x input rows).
__device__ __forceinline__ void mm_glb(f32x4 acc[2], const f16* __restrict__ arow,
                                       const f16* __restrict__ wt, int w, int q, int mn) {
#pragma unroll
  for (int kt = 0; kt < 8; ++kt) {
    const int k0 = kt * 32 + q * 8;
    f16x8 a = *(const f16x8*)(arow + k0);
#pragma unroll
    for (int nt = 0; nt < 2; ++nt) {
      f16x8 b = *(const f16x8*)(wt + (size_t)(w * 32 + nt * 16 + mn) * 256 + k0);
      acc[nt] = __builtin_amdgcn_mfma_f32_16x16x32_f16(a, b, acc[nt], 0, 0, 0);
    }
  }
}

__global__ __launch_bounds__(512, 1) void rnn_kernel(
    const f16* __restrict__ xh,        // [B][T][D] fp16
    const float* __restrict__ hidden,  // [2][B][H] f32
    const f16* __restrict__ Win0T, const f16* __restrict__ Wh0T, const float* __restrict__ b0,
    const f16* __restrict__ Win1T, const f16* __restrict__ Wh1T, const float* __restrict__ b1,
    float* __restrict__ out) {         // [B][T][H] ++ [2][B][H]
  __shared__ f16 hbuf0[16][APAD];
  __shared__ f16 hbuf1[16][APAD];
  __shared__ f16 nbuf[16][APAD];

  const int tid = threadIdx.x;
  const int lane = tid & 63;
  const int w = tid >> 6;        // wave 0..7, owns output cols [w*32, w*32+32)
  const int q = lane >> 4;       // quad
  const int mn = lane & 15;      // A-row (as A operand) / D-col (as C/D)
  const int rb = blockIdx.x << 4;

  // init recurrent states (f32 -> fp16)
  for (int i = tid; i < 16 * 256; i += 512) {
    const int m = i >> 8, n = i & 255;
    hbuf0[m][n] = (f16)hidden[(size_t)(rb + m) * 256 + n];
    hbuf1[m][n] = (f16)hidden[(size_t)(128 + rb + m) * 256 + n];
  }
  __syncthreads();

  const int nc = w * 32 + mn;                 // base col (nt adds 16)
  const f16* xrow_b = xh + (size_t)(rb + mn) * Tt * 256;
  const int dr = q * 4;                       // D row base for this lane

  float n0v[2][4], n1v[2][4];

  for (int t = 0; t < Tt; ++t) {
    const f16* wI0 = Win0T + (size_t)t * 65536;
    const f16* wH0 = Wh0T + (size_t)t * 3 * 65536;
    const f16* wI1 = Win1T + (size_t)t * 65536;
    const f16* wH1 = Wh1T + (size_t)t * 3 * 65536;
    const float* bb0 = b0 + (size_t)t * 3 * 256;
    const float* bb1 = b1 + (size_t)t * 3 * 256;

    // ================= LAYER 0 =================
    { // node 0: tanh(x@Win0 + h0@Wh0[0] + b0[0])
      f32x4 acc[2] = {{0.f,0.f,0.f,0.f},{0.f,0.f,0.f,0.f}};
      mm_glb(acc, xrow_b + (size_t)t * 256, wI0, w, q, mn);
      mm_lds(acc, &hbuf0[mn][0], wH0, w, q, mn);
#pragma unroll
      for (int nt = 0; nt < 2; ++nt) {
        const float bv = bb0[nc + nt * 16];
#pragma unroll
        for (int r = 0; r < 4; ++r) n0v[nt][r] = tanhf(acc[nt][r] + bv);
      }
    }
    __syncthreads();
#pragma unroll
    for (int nt = 0; nt < 2; ++nt)
#pragma unroll
      for (int r = 0; r < 4; ++r) nbuf[dr + r][nc + nt * 16] = (f16)n0v[nt][r];
    __syncthreads();

    { // node 1: relu(n0@Wh0[1] + b0[1]) + n0
      f32x4 acc[2] = {{0.f,0.f,0.f,0.f},{0.f,0.f,0.f,0.f}};
      mm_lds(acc, &nbuf[mn][0], wH0 + 65536, w, q, mn);
#pragma unroll
      for (int nt = 0; nt < 2; ++nt) {
        const float bv = bb0[256 + nc + nt * 16];
#pragma unroll
        for (int r = 0; r < 4; ++r) n1v[nt][r] = fmaxf(acc[nt][r] + bv, 0.f) + n0v[nt][r];
      }
    }
    __syncthreads();
#pragma unroll
    for (int nt = 0; nt < 2; ++nt)
#pragma unroll
      for (int r = 0; r < 4; ++r) nbuf[dr + r][nc + nt * 16] = (f16)n1v[nt][r];
    __syncthreads();

    { // node 2: sigmoid(n1@Wh0[2] + b0[2]) + n0 ; h0' = 0.5*(n1+n2)
      f32x4 acc[2] = {{0.f,0.f,0.f,0.f},{0.f,0.f,0.f,0.f}};
      mm_lds(acc, &nbuf[mn][0], wH0 + 2 * 65536, w, q, mn);
#pragma unroll
      for (int nt = 0; nt < 2; ++nt) {
        const float bv = bb0[512 + nc + nt * 16];
#pragma unroll
        for (int r = 0; r < 4; ++r) {
          const float s = 1.f / (1.f + __expf(-(acc[nt][r] + bv)));
          const float n2 = s + n0v[nt][r];
          const float hv = 0.5f * (n1v[nt][r] + n2);
          hbuf0[dr + r][nc + nt * 16] = (f16)hv;   // safe: hbuf0 readers (L0 n0) long past barriers
          if (t == Tt - 1)
            out[2097152 + (size_t)(rb + dr + r) * 256 + nc + nt * 16] = hv;
        }
      }
    }
    __syncthreads();

    // ================= LAYER 1 =================  (input = h0' in hbuf0)
    { // node 0: tanh(out0@Win1 + h1@Wh1[0] + b1[0])
      f32x4 acc[2] = {{0.f,0.f,0.f,0.f},{0.f,0.f,0.f,0.f}};
      mm_lds(acc, &hbuf0[mn][0], wI1, w, q, mn);
      mm_lds(acc, &hbuf1[mn][0], wH1, w, q, mn);
#pragma unroll
      for (int nt = 0; nt < 2; ++nt) {
        const float bv = bb1[nc + nt * 16];
#pragma unroll
        for (int r = 0; r < 4; ++r) n0v[nt][r] = tanhf(acc[nt][r] + bv);
      }
    }
    __syncthreads();
#pragma unroll
    for (int nt = 0; nt < 2; ++nt)
#pragma unroll
      for (int r = 0; r < 4; ++r) nbuf[dr + r][nc + nt * 16] = (f16)n0v[nt][r];
    __syncthreads();

    { // node 1
      f32x4 acc[2] = {{0.f,0.f,0.f,0.f},{0.f,0.f,0.f,0.f}};
      mm_lds(acc, &nbuf[mn][0], wH1 + 65536, w, q, mn);
#pragma unroll
      for (int nt = 0; nt < 2; ++nt) {
        const float bv = bb1[256 + nc + nt * 16];
#pragma unroll
        for (int r = 0; r < 4; ++r) n1v[nt][r] = fmaxf(acc[nt][r] + bv, 0.f) + n0v[nt][r];
      }
    }
    __syncthreads();
#pragma unroll
    for (int nt = 0; nt < 2; ++nt)
#pragma unroll
      for (int r = 0; r < 4; ++r) nbuf[dr + r][nc + nt * 16] = (f16)n1v[nt][r];
    __syncthreads();

    { // node 2 + h1' + output write
      f32x4 acc[2] = {{0.f,0.f,0.f,0.f},{0.f,0.f,0.f,0.f}};
      mm_lds(acc, &nbuf[mn][0], wH1 + 2 * 65536, w, q, mn);
#pragma unroll
      for (int nt = 0; nt < 2; ++nt) {
        const float bv = bb1[512 + nc + nt * 16];
#pragma unroll
        for (int r = 0; r < 4; ++r) {
          const float s = 1.f / (1.f + __expf(-(acc[nt][r] + bv)));
          const float n2 = s + n0v[nt][r];
          const float hv = 0.5f * (n1v[nt][r] + n2);
          hbuf1[dr + r][nc + nt * 16] = (f16)hv;
          out[((size_t)(rb + dr + r) * Tt + t) * 256 + nc + nt * 16] = hv;  // output[b][t][h]
          if (t == Tt - 1)
            out[2097152 + 32768 + (size_t)(rb + dr + r) * 256 + nc + nt * 16] = hv;
        }
      }
    }
    __syncthreads();
  }
}

// ---------------- launch ----------------
extern "C" void kernel_launch(void* const* d_in, const int* in_sizes, int n_in,
                              void* d_out, int out_size, void* d_ws, size_t ws_size,
                              hipStream_t stream) {
  (void)in_sizes; (void)n_in; (void)out_size; (void)ws_size;
  const float* x      = (const float*)d_in[0];
  const float* hidden = (const float*)d_in[1];
  const float* Win0   = (const float*)d_in[2];
  const float* Wh0    = (const float*)d_in[3];
  const float* b0     = (const float*)d_in[4];
  const float* Win1   = (const float*)d_in[5];
  const float* Wh1    = (const float*)d_in[6];
  const float* b1     = (const float*)d_in[7];
  float* out = (float*)d_out;

  // ws layout (fp16 elements); total 35,651,584 * 2B = 71,303,168 bytes
  f16* ws    = (f16*)d_ws;
  f16* xh    = ws;                  // 2,097,152
  f16* Win0T = ws + 2097152;        // 4,194,304
  f16* Wh0T  = ws + 6291456;        // 12,582,912
  f16* Win1T = ws + 18874368;       // 4,194,304
  f16* Wh1T  = ws + 23068672;       // 12,582,912

  cvt_x_kernel<<<dim3(2048), dim3(256), 0, stream>>>(x, xh, 128 * 64 * 256);
  transpose_cvt_kernel<<<dim3(32768), dim3(256), 0, stream>>>(
      Win0, Wh0, Win1, Wh1, Win0T, Wh0T, Win1T, Wh1T);
  rnn_kernel<<<dim3(8), dim3(512), 0, stream>>>(
      xh, hidden, Win0T, Wh0T, b0, Win1T, Wh1T, b1, out);
}

// Round 2
// 1834.247 us; speedup vs baseline: 1.3048x; 1.3048x over previous
//
#include <hip/hip_runtime.h>

// CustomRNN: B=128, T=64, D=H=256, L=2, 3-node cell
//   n0 = tanh(x@Win + h@Wh0 + b0); n1 = relu(n0@Wh1 + b1) + n0;
//   n2 = sigmoid(n1@Wh2 + b2) + n0; h' = 0.5*(n1+n2)
// Round 2: register double-buffered weight prefetch (fix latency serialization
// seen as VGPR_Count=64 in round 1), precomputed x@Win0+b0[0], 1 barrier/matmul.

typedef _Float16 f16;
typedef __attribute__((ext_vector_type(8))) _Float16 f16x8;
typedef __attribute__((ext_vector_type(4))) float f32x4;

#define Tt 64
#define APAD 264   // f16 row stride: 528B = 132 dwords; 132%32=4 -> 2-way LDS aliasing (free)

// ---------------- transpose+convert: [k][n] f32 -> [n][k] f16 ----------------
// 512 matrices: 64 Win0 + 192 Wh0 + 64 Win1 + 192 Wh1
__global__ void transpose_cvt_kernel(const float* __restrict__ Win0, const float* __restrict__ Wh0,
                                     const float* __restrict__ Win1, const float* __restrict__ Wh1,
                                     f16* __restrict__ Win0T, f16* __restrict__ Wh0T,
                                     f16* __restrict__ Win1T, f16* __restrict__ Wh1T) {
  __shared__ float tile[32][33];
  const int bid = blockIdx.x;
  const int mat = bid >> 6, tl = bid & 63;
  const int k0 = (tl & 7) << 5, n0 = (tl >> 3) << 5;
  const float* src; f16* dst;
  if (mat < 64)       { src = Win0 + (size_t)mat * 65536;         dst = Win0T + (size_t)mat * 65536; }
  else if (mat < 256) { src = Wh0  + (size_t)(mat - 64) * 65536;  dst = Wh0T  + (size_t)(mat - 64) * 65536; }
  else if (mat < 320) { src = Win1 + (size_t)(mat - 256) * 65536; dst = Win1T + (size_t)(mat - 256) * 65536; }
  else                { src = Wh1  + (size_t)(mat - 320) * 65536; dst = Wh1T  + (size_t)(mat - 320) * 65536; }
  const int c = threadIdx.x & 31, r0 = threadIdx.x >> 5;
#pragma unroll
  for (int it = 0; it < 4; ++it) {
    const int r = r0 + it * 8;
    tile[r][c] = src[(k0 + r) * 256 + n0 + c];
  }
  __syncthreads();
#pragma unroll
  for (int it = 0; it < 4; ++it) {
    const int r = r0 + it * 8;
    dst[(size_t)(n0 + r) * 256 + k0 + c] = (f16)tile[c][r];   // dst[n][k] = src[k][n]
  }
}

// ---------------- MFMA helpers ----------------
// mfma_f32_16x16x32_f16: A: lane holds A[m=lane&15][k=(lane>>4)*8+j]
//                        B: lane holds B[k=(lane>>4)*8+j][n=lane&15] (W^T rows contiguous)
//                        C/D: reg r holds D[row=(lane>>4)*4+r][col=lane&15]

__device__ __forceinline__ void ldw(f16x8 (&wf)[16], const f16* __restrict__ wt,
                                    int nc, int q) {
#pragma unroll
  for (int kt = 0; kt < 8; ++kt)
#pragma unroll
    for (int nt = 0; nt < 2; ++nt)
      wf[kt * 2 + nt] = *(const f16x8*)(wt + (size_t)(nc + nt * 16) * 256 + kt * 32 + q * 8);
}

__device__ __forceinline__ void mmf(f32x4 (&acc)[2], const f16* abase,
                                    const f16x8 (&wf)[16], int q) {
#pragma unroll
  for (int kt = 0; kt < 8; ++kt) {
    f16x8 a = *(const f16x8*)(abase + kt * 32 + q * 8);
    acc[0] = __builtin_amdgcn_mfma_f32_16x16x32_f16(a, wf[kt * 2 + 0], acc[0], 0, 0, 0);
    acc[1] = __builtin_amdgcn_mfma_f32_16x16x32_f16(a, wf[kt * 2 + 1], acc[1], 0, 0, 0);
  }
}

// ---------------- xw precompute: xw[t,b,h] = x[b,t,:]@Win0[t] + b0[t,0,h] ----------------
__global__ __launch_bounds__(512, 2) void xw_kernel(
    const float* __restrict__ x, const f16* __restrict__ Win0T,
    const float* __restrict__ b0, float* __restrict__ xw) {
  const int t = blockIdx.x >> 3, bb = blockIdx.x & 7;
  const int rb = bb << 4;
  const int tid = threadIdx.x, lane = tid & 63, w = tid >> 6;
  const int q = lane >> 4, mn = lane & 15;
  const int nc = w * 32 + mn, dr = q * 4;
  const f16* wt = Win0T + (size_t)t * 65536;
  const float* xrow = x + ((size_t)(rb + mn) * Tt + t) * 256;
  f32x4 acc[2] = {{0.f,0.f,0.f,0.f},{0.f,0.f,0.f,0.f}};
#pragma unroll
  for (int kt = 0; kt < 8; ++kt) {
    const int k0 = kt * 32 + q * 8;
    f16x8 a;
#pragma unroll
    for (int j = 0; j < 8; ++j) a[j] = (f16)xrow[k0 + j];
#pragma unroll
    for (int nt = 0; nt < 2; ++nt) {
      f16x8 b = *(const f16x8*)(wt + (size_t)(nc + nt * 16) * 256 + k0);
      acc[nt] = __builtin_amdgcn_mfma_f32_16x16x32_f16(a, b, acc[nt], 0, 0, 0);
    }
  }
#pragma unroll
  for (int nt = 0; nt < 2; ++nt) {
    const float bv = b0[(size_t)t * 768 + nc + nt * 16];
#pragma unroll
    for (int r = 0; r < 4; ++r)
      xw[(size_t)t * 32768 + (size_t)(rb + dr + r) * 256 + nc + nt * 16] = acc[nt][r] + bv;
  }
}

// ---------------- one RNN timestep (weights ping-pong A<->B) ----------------
__device__ __forceinline__ void rnn_step(
    int t, f16x8 (&A)[16], f16x8 (&B)[16],
    f16 (*hbuf0)[APAD], f16 (*hbuf1)[APAD], f16 (*nbufA)[APAD], f16 (*nbufB)[APAD],
    const f16* __restrict__ Wh0T, const f16* __restrict__ Win1T, const f16* __restrict__ Wh1T,
    const float* __restrict__ b0, const float* __restrict__ b1,
    const float* __restrict__ xw, float* __restrict__ out,
    int rb, int q, int mn, int nc, int dr) {
  const f16* wH0 = Wh0T + (size_t)t * 3 * 65536;
  const f16* wI1 = Win1T + (size_t)t * 65536;
  const f16* wH1 = Wh1T + (size_t)t * 3 * 65536;
  const float* bb0 = b0 + (size_t)t * 768;
  const float* bb1 = b1 + (size_t)t * 768;
  const bool last = (t == Tt - 1);
  float n0v[2][4], n1v[2][4];

  // ---- m0: n0 = tanh(h0@Wh0[0] + xw) ----  (A holds Wh0[0], prefetched)
  {
    float xwv[2][4];
#pragma unroll
    for (int nt = 0; nt < 2; ++nt)
#pragma unroll
      for (int r = 0; r < 4; ++r)
        xwv[nt][r] = xw[(size_t)t * 32768 + (size_t)(rb + dr + r) * 256 + nc + nt * 16];
    ldw(B, wH0 + 65536, nc, q);                       // prefetch m1 (Wh0[1])
    f32x4 acc[2] = {{0.f,0.f,0.f,0.f},{0.f,0.f,0.f,0.f}};
    mmf(acc, &hbuf0[mn][0], A, q);
#pragma unroll
    for (int nt = 0; nt < 2; ++nt)
#pragma unroll
      for (int r = 0; r < 4; ++r) {
        n0v[nt][r] = tanhf(acc[nt][r] + xwv[nt][r]);
        nbufA[dr + r][nc + nt * 16] = (f16)n0v[nt][r];
      }
  }
  __syncthreads();

  // ---- m1: n1 = relu(n0@Wh0[1] + b0[1]) + n0 ----  (B)
  {
    ldw(A, wH0 + 2 * 65536, nc, q);                   // prefetch m2 (Wh0[2])
    const float bv0 = bb0[256 + nc], bv1 = bb0[256 + nc + 16];
    f32x4 acc[2] = {{0.f,0.f,0.f,0.f},{0.f,0.f,0.f,0.f}};
    mmf(acc, &nbufA[mn][0], B, q);
#pragma unroll
    for (int nt = 0; nt < 2; ++nt) {
      const float bv = nt ? bv1 : bv0;
#pragma unroll
      for (int r = 0; r < 4; ++r) {
        n1v[nt][r] = fmaxf(acc[nt][r] + bv, 0.f) + n0v[nt][r];
        nbufB[dr + r][nc + nt * 16] = (f16)n1v[nt][r];
      }
    }
  }
  __syncthreads();

  // ---- m2: n2 = sigmoid(n1@Wh0[2] + b0[2]) + n0; h0' = 0.5*(n1+n2) ----  (A)
  {
    ldw(B, wI1, nc, q);                               // prefetch m3 (Win1)
    const float bv0 = bb0[512 + nc], bv1 = bb0[512 + nc + 16];
    f32x4 acc[2] = {{0.f,0.f,0.f,0.f},{0.f,0.f,0.f,0.f}};
    mmf(acc, &nbufB[mn][0], A, q);
#pragma unroll
    for (int nt = 0; nt < 2; ++nt) {
      const float bv = nt ? bv1 : bv0;
#pragma unroll
      for (int r = 0; r < 4; ++r) {
        const float s = 1.f / (1.f + __expf(-(acc[nt][r] + bv)));
        const float hv = 0.5f * (n1v[nt][r] + s + n0v[nt][r]);
        hbuf0[dr + r][nc + nt * 16] = (f16)hv;
        if (last) out[2097152 + (size_t)(rb + dr + r) * 256 + nc + nt * 16] = hv;
      }
    }
  }
  __syncthreads();

  // ---- m3+m4: n0' = tanh(h0'@Win1 + h1@Wh1[0] + b1[0]) ----  (B then A)
  {
    ldw(A, wH1, nc, q);                               // prefetch m4 (Wh1[0])
    const float bv0 = bb1[nc], bv1 = bb1[nc + 16];
    f32x4 acc[2] = {{0.f,0.f,0.f,0.f},{0.f,0.f,0.f,0.f}};
    mmf(acc, &hbuf0[mn][0], B, q);                    // h0' @ Win1
    ldw(B, wH1 + 65536, nc, q);                       // prefetch m5 (Wh1[1])
    mmf(acc, &hbuf1[mn][0], A, q);                    // h1 @ Wh1[0]
#pragma unroll
    for (int nt = 0; nt < 2; ++nt) {
      const float bv = nt ? bv1 : bv0;
#pragma unroll
      for (int r = 0; r < 4; ++r) {
        n0v[nt][r] = tanhf(acc[nt][r] + bv);
        nbufA[dr + r][nc + nt * 16] = (f16)n0v[nt][r];
      }
    }
  }
  __syncthreads();

  // ---- m5: n1' = relu(n0'@Wh1[1] + b1[1]) + n0' ----  (B)
  {
    ldw(A, wH1 + 2 * 65536, nc, q);                   // prefetch m6 (Wh1[2])
    const float bv0 = bb1[256 + nc], bv1 = bb1[256 + nc + 16];
    f32x4 acc[2] = {{0.f,0.f,0.f,0.f},{0.f,0.f,0.f,0.f}};
    mmf(acc, &nbufA[mn][0], B, q);
#pragma unroll
    for (int nt = 0; nt < 2; ++nt) {
      const float bv = nt ? bv1 : bv0;
#pragma unroll
      for (int r = 0; r < 4; ++r) {
        n1v[nt][r] = fmaxf(acc[nt][r] + bv, 0.f) + n0v[nt][r];
        nbufB[dr + r][nc + nt * 16] = (f16)n1v[nt][r];
      }
    }
  }
  __syncthreads();

  // ---- m6: n2' = sigmoid(n1'@Wh1[2] + b1[2]) + n0'; h1' = 0.5*(n1'+n2') ----  (A)
  {
    const f16* wNext = Wh0T + (size_t)(last ? t : t + 1) * 3 * 65536;
    ldw(B, wNext, nc, q);                             // prefetch next step m0 (Wh0[0])
    const float bv0 = bb1[512 + nc], bv1 = bb1[512 + nc + 16];
    f32x4 acc[2] = {{0.f,0.f,0.f,0.f},{0.f,0.f,0.f,0.f}};
    mmf(acc, &nbufB[mn][0], A, q);
#pragma unroll
    for (int nt = 0; nt < 2; ++nt) {
      const float bv = nt ? bv1 : bv0;
#pragma unroll
      for (int r = 0; r < 4; ++r) {
        const float s = 1.f / (1.f + __expf(-(acc[nt][r] + bv)));
        const float hv = 0.5f * (n1v[nt][r] + s + n0v[nt][r]);
        hbuf1[dr + r][nc + nt * 16] = (f16)hv;
        out[((size_t)(rb + dr + r) * Tt + t) * 256 + nc + nt * 16] = hv;
        if (last) out[2097152 + 32768 + (size_t)(rb + dr + r) * 256 + nc + nt * 16] = hv;
      }
    }
  }
  __syncthreads();
}

// ---------------- recurrent kernel: 8 WGs x 16 batch rows ----------------
__global__ __launch_bounds__(512, 2) void rnn_kernel(
    const float* __restrict__ hidden,
    const f16* __restrict__ Wh0T, const float* __restrict__ b0,
    const f16* __restrict__ Win1T, const f16* __restrict__ Wh1T, const float* __restrict__ b1,
    const float* __restrict__ xw, float* __restrict__ out) {
  __shared__ f16 hbuf0[16][APAD];
  __shared__ f16 hbuf1[16][APAD];
  __shared__ f16 nbufA[16][APAD];
  __shared__ f16 nbufB[16][APAD];

  const int tid = threadIdx.x;
  const int lane = tid & 63;
  const int w = tid >> 6;
  const int q = lane >> 4;
  const int mn = lane & 15;
  const int rb = blockIdx.x << 4;
  const int nc = w * 32 + mn;
  const int dr = q * 4;

  for (int i = tid; i < 16 * 256; i += 512) {
    const int m = i >> 8, n = i & 255;
    hbuf0[m][n] = (f16)hidden[(size_t)(rb + m) * 256 + n];
    hbuf1[m][n] = (f16)hidden[(size_t)(128 + rb + m) * 256 + n];
  }

  f16x8 wf0[16], wf1[16];
  ldw(wf0, Wh0T, nc, q);   // t=0 m0 weights
  __syncthreads();

#pragma unroll 1
  for (int t2 = 0; t2 < Tt / 2; ++t2) {
    rnn_step(2 * t2,     wf0, wf1, hbuf0, hbuf1, nbufA, nbufB,
             Wh0T, Win1T, Wh1T, b0, b1, xw, out, rb, q, mn, nc, dr);
    rnn_step(2 * t2 + 1, wf1, wf0, hbuf0, hbuf1, nbufA, nbufB,
             Wh0T, Win1T, Wh1T, b0, b1, xw, out, rb, q, mn, nc, dr);
  }
}

// ---------------- launch ----------------
extern "C" void kernel_launch(void* const* d_in, const int* in_sizes, int n_in,
                              void* d_out, int out_size, void* d_ws, size_t ws_size,
                              hipStream_t stream) {
  (void)in_sizes; (void)n_in; (void)out_size; (void)ws_size;
  const float* x      = (const float*)d_in[0];
  const float* hidden = (const float*)d_in[1];
  const float* Win0   = (const float*)d_in[2];
  const float* Wh0    = (const float*)d_in[3];
  const float* b0     = (const float*)d_in[4];
  const float* Win1   = (const float*)d_in[5];
  const float* Wh1    = (const float*)d_in[6];
  const float* b1     = (const float*)d_in[7];
  float* out = (float*)d_out;

  // ws layout: f16 weights then f32 xw. Total 75,497,472 bytes.
  f16* ws    = (f16*)d_ws;
  f16* Win0T = ws;                  //  4,194,304 f16
  f16* Wh0T  = ws + 4194304;        // 12,582,912 f16
  f16* Win1T = ws + 16777216;       //  4,194,304 f16
  f16* Wh1T  = ws + 20971520;       // 12,582,912 f16
  float* xw  = (float*)(ws + 33554432);  // 2,097,152 f32

  transpose_cvt_kernel<<<dim3(32768), dim3(256), 0, stream>>>(
      Win0, Wh0, Win1, Wh1, Win0T, Wh0T, Win1T, Wh1T);
  xw_kernel<<<dim3(512), dim3(512), 0, stream>>>(x, Win0T, b0, xw);
  rnn_kernel<<<dim3(8), dim3(512), 0, stream>>>(
      hidden, Wh0T, b0, Win1T, Wh1T, b1, xw, out);
}

// Round 3
// 1390.022 us; speedup vs baseline: 1.7218x; 1.3196x over previous
//
#include <hip/hip_runtime.h>

// CustomRNN: B=128, T=64, D=H=256, L=2, 3-node cell.
// Round 3: weights streamed via async global_load_lds into per-wave LDS slices
// (2 K-half buffers, ping-pong), lgkm-only barriers (weight DMAs survive
// barriers), manual vmcnt pipeline discipline, biases DMA'd to LDS, xw
// prefetched a step ahead. 8 WGs x 16 batch rows, zero inter-WG sync.

typedef _Float16 f16;
typedef __attribute__((ext_vector_type(8))) _Float16 f16x8;
typedef __attribute__((ext_vector_type(4))) float f32x4;
typedef __attribute__((ext_vector_type(4))) float float4v;

#define Tt 64

// ---------------- helpers ----------------
__device__ __forceinline__ void sb() { __builtin_amdgcn_sched_barrier(0); }

template <int N>
__device__ __forceinline__ void waitvm() {
  // s_waitcnt vmcnt(N), lgkm=15 (no wait), exp=7 (no wait); gfx9 encoding
  __builtin_amdgcn_s_waitcnt(0x0F70 | (N & 15) | ((N >> 4) << 14));
}
__device__ __forceinline__ void waitlgkm0() { __builtin_amdgcn_s_waitcnt(0xC07F); }

__device__ __forceinline__ void barx() {
  // barrier that drains LDS ops only -- weight DMAs (vmcnt) stay in flight
  asm volatile("s_waitcnt lgkmcnt(0)\n\ts_barrier" ::: "memory");
}

__device__ __forceinline__ void dma16(const void* g, void* l) {
  __builtin_amdgcn_global_load_lds(
      (const __attribute__((address_space(1))) unsigned int*)g,
      (__attribute__((address_space(3))) unsigned int*)l, 16, 0, 0);
}
__device__ __forceinline__ void dma8x(const char* g, char* l) {
#pragma unroll
  for (int d = 0; d < 8; ++d) dma16(g + d * 2048, l + d * 1024);
}

__device__ __forceinline__ float tanh_fast(float x) {
  float xc = fminf(fmaxf(x, -15.f), 15.f);
  float e = __expf(2.f * xc);
  return (e - 1.f) / (e + 1.f);
}
__device__ __forceinline__ float sigmoid_fast(float x) { return 1.f / (1.f + __expf(-x)); }

// ---------------- transpose+convert: [k][n] f32 -> [n][k] f16 ----------------
__global__ void transpose_cvt_kernel(const float* __restrict__ Win0, const float* __restrict__ Wh0,
                                     const float* __restrict__ Win1, const float* __restrict__ Wh1,
                                     f16* __restrict__ Win0T, f16* __restrict__ Wh0T,
                                     f16* __restrict__ Win1T, f16* __restrict__ Wh1T) {
  __shared__ float tile[32][33];
  const int bid = blockIdx.x;
  const int mat = bid >> 6, tl = bid & 63;
  const int k0 = (tl & 7) << 5, n0 = (tl >> 3) << 5;
  const float* src; f16* dst;
  if (mat < 64)       { src = Win0 + (size_t)mat * 65536;         dst = Win0T + (size_t)mat * 65536; }
  else if (mat < 256) { src = Wh0  + (size_t)(mat - 64) * 65536;  dst = Wh0T  + (size_t)(mat - 64) * 65536; }
  else if (mat < 320) { src = Win1 + (size_t)(mat - 256) * 65536; dst = Win1T + (size_t)(mat - 256) * 65536; }
  else                { src = Wh1  + (size_t)(mat - 320) * 65536; dst = Wh1T  + (size_t)(mat - 320) * 65536; }
  const int c = threadIdx.x & 31, r0 = threadIdx.x >> 5;
#pragma unroll
  for (int it = 0; it < 4; ++it) {
    const int r = r0 + it * 8;
    tile[r][c] = src[(k0 + r) * 256 + n0 + c];
  }
  __syncthreads();
  // write [n][k] as packed f16 pairs (4B stores)
#pragma unroll
  for (int it = 0; it < 2; ++it) {
    const int nn = (threadIdx.x >> 4) + it * 16;
    const int kk2 = (threadIdx.x & 15) * 2;
    f16 lo = (f16)tile[kk2][nn], hi = (f16)tile[kk2 + 1][nn];
    unsigned short ulo = *(unsigned short*)&lo, uhi = *(unsigned short*)&hi;
    unsigned u = (unsigned)ulo | ((unsigned)uhi << 16);
    *(unsigned*)((char*)dst + ((size_t)(n0 + nn) * 256 + k0 + kk2) * 2) = u;
  }
}

// ---------------- xw precompute: xw[t,b,h] = x[b,t,:]@Win0[t] + b0[t,0,h] ----------------
__global__ __launch_bounds__(512, 2) void xw_kernel(
    const float* __restrict__ x, const f16* __restrict__ Win0T,
    const float* __restrict__ b0, float* __restrict__ xw) {
  const int t = blockIdx.x >> 3, bb = blockIdx.x & 7;
  const int rb = bb << 4;
  const int tid = threadIdx.x, lane = tid & 63, w = tid >> 6;
  const int q = lane >> 4, mn = lane & 15;
  const int nc = w * 32 + mn, dr = q * 4;
  const f16* wt = Win0T + (size_t)t * 65536;
  const float4v* xr = (const float4v*)(x + ((size_t)(rb + mn) * Tt + t) * 256);
  f32x4 acc[2] = {{0.f,0.f,0.f,0.f},{0.f,0.f,0.f,0.f}};
#pragma unroll
  for (int kt = 0; kt < 8; ++kt) {
    const int k0 = kt * 32 + q * 8;
    float4v x0 = xr[k0 / 4], x1 = xr[k0 / 4 + 1];
    f16x8 a = {(f16)x0.x, (f16)x0.y, (f16)x0.z, (f16)x0.w,
               (f16)x1.x, (f16)x1.y, (f16)x1.z, (f16)x1.w};
#pragma unroll
    for (int nt = 0; nt < 2; ++nt) {
      f16x8 b = *(const f16x8*)(wt + (size_t)(nc + nt * 16) * 256 + k0);
      acc[nt] = __builtin_amdgcn_mfma_f32_16x16x32_f16(a, b, acc[nt], 0, 0, 0);
    }
  }
#pragma unroll
  for (int nt = 0; nt < 2; ++nt) {
    const float bv = b0[(size_t)t * 768 + nc + nt * 16];
#pragma unroll
    for (int r = 0; r < 4; ++r)
      xw[(size_t)t * 32768 + (size_t)(rb + dr + r) * 256 + nc + nt * 16] = acc[nt][r] + bv;
  }
}

// ---------------- one matmul K-half phase ----------------
// Reads A-frags from an activation buffer row, B-frags from this wave's LDS
// weight half-buffer, then DMAs the NEXT matmul's corresponding half into the
// same buffer, then runs the 8 MFMAs.
template <int NW>
__device__ __forceinline__ void phase(f32x4 (&acc)[2], const char* arow, const char* wb,
                                      const char* gnext, char* lnext, int q, int mn) {
  waitvm<NW>();   // our half's DMA has landed
  sb();
  f16x8 a[4], b[8];
#pragma unroll
  for (int kt = 0; kt < 4; ++kt) {
    a[kt]         = *(const f16x8*)(arow + kt * 64 + q * 16);
    b[kt * 2]     = *(const f16x8*)(wb + mn * 256 + kt * 64 + q * 16);
    b[kt * 2 + 1] = *(const f16x8*)(wb + (16 + mn) * 256 + kt * 64 + q * 16);
  }
  sb();
  waitlgkm0();            // reads executed -> safe to overwrite buffer
  dma8x(gnext, lnext);    // prefetch next matmul's half (async, no VGPRs)
  sb();
#pragma unroll
  for (int kt = 0; kt < 4; ++kt) {
    acc[0] = __builtin_amdgcn_mfma_f32_16x16x32_f16(a[kt], b[kt * 2],     acc[0], 0, 0, 0);
    acc[1] = __builtin_amdgcn_mfma_f32_16x16x32_f16(a[kt], b[kt * 2 + 1], acc[1], 0, 0, 0);
  }
}

// ---------------- recurrent kernel: 8 WGs x 16 batch rows ----------------
__global__ __launch_bounds__(512, 1) void rnn_kernel(
    const float* __restrict__ hidden,
    const f16* __restrict__ Wh0T, const float* __restrict__ b0,
    const f16* __restrict__ Win1T, const f16* __restrict__ Wh1T, const float* __restrict__ b1,
    const float* __restrict__ xw, float* __restrict__ out) {
  // LDS: [0,128K) per-wave weight slices (16KB each: bufA 8K + bufB 8K)
  //      then hbuf0/hbuf1/nbuf (16 rows x 264 f16 = 8448B each), then bias 5KB
  __shared__ __align__(16) char smem[161536];
  char* wlds  = smem;
  char* hbuf0 = smem + 131072;
  char* hbuf1 = smem + 139520;
  char* nbuf  = smem + 147968;
  char* biasl = smem + 156416;

  const int tid = threadIdx.x;
  const int lane = tid & 63;
  const int w = tid >> 6;
  const int q = lane >> 4;
  const int mn = lane & 15;
  const int rb = blockIdx.x << 4;
  const int nc = w * 32 + mn;
  const int dr = q * 4;
  const int laneoff = (lane >> 4) * 512 + (lane & 15) * 16;

  // hidden f32 -> f16 into hbuf0/hbuf1
  for (int i = tid; i < 16 * 256; i += 512) {
    const int m = i >> 8, n = i & 255;
    *(f16*)(hbuf0 + m * 528 + n * 2) = (f16)hidden[(size_t)(rb + m) * 256 + n];
    *(f16*)(hbuf1 + m * 528 + n * 2) = (f16)hidden[(size_t)(128 + rb + m) * 256 + n];
  }
  barx();

  char* bufA = wlds + w * 16384;
  char* bufB = bufA + 8192;
  const char* Wh0b  = (const char*)Wh0T;
  const char* Win1b = (const char*)Win1T;
  const char* Wh1b  = (const char*)Wh1T;
  const char* b0c = (const char*)b0;
  const char* b1c = (const char*)b1;

  // prelude: DMA t=0 m0 weights (Wh0[0][0]) halves, then xw(t=0) prefetch
  {
    const char* g = Wh0b + w * 16384 + laneoff;
    dma8x(g, bufA);
    dma8x(g + 256, bufB);
    sb();
  }
  float xwn[2][4];
#pragma unroll
  for (int nt = 0; nt < 2; ++nt)
#pragma unroll
    for (int r = 0; r < 4; ++r)
      xwn[nt][r] = xw[(size_t)(rb + dr + r) * 256 + nc + nt * 16];
  sb();

  float n0v[2][4], n1v[2][4];
  const f32x4 zero4 = {0.f, 0.f, 0.f, 0.f};

#pragma unroll 1
  for (int t = 0; t < Tt; ++t) {
    const int tn = (t < Tt - 1) ? t + 1 : t;
    const bool last = (t == Tt - 1);
    const char* wH0t = Wh0b + (size_t)t * 393216 + w * 16384 + laneoff;
    const char* wI1t = Win1b + (size_t)t * 131072 + w * 16384 + laneoff;
    const char* wH1t = Wh1b + (size_t)t * 393216 + w * 16384 + laneoff;
    const char* wH0n = Wh0b + (size_t)tn * 393216 + w * 16384 + laneoff;

    // step-start: bias DMA (b0[t][1..2] -> idx0,1 ; b1[t][0..2] -> idx2..4)
    {
      const char* g0 = b0c + (size_t)t * 3072 + 1024 + lane * 16;
      dma16(g0, biasl);
      dma16(g0 + 1024, biasl + 1024);
      const char* g1 = b1c + (size_t)t * 3072 + lane * 16;
      dma16(g1, biasl + 2048);
      dma16(g1 + 1024, biasl + 3072);
      dma16(g1 + 2048, biasl + 4096);
      sb();
    }

    f32x4 acc[2];

    // ---- m0: n0 = tanh(h0@Wh0[0] + xw) ; prefetch Wh0[1]
    acc[0] = zero4; acc[1] = zero4;
    phase<21>(acc, hbuf0 + mn * 528,       bufA, wH0t + 131072,       bufA, q, mn);
    phase<21>(acc, hbuf0 + mn * 528 + 256, bufB, wH0t + 131072 + 256, bufB, q, mn);
#pragma unroll
    for (int nt = 0; nt < 2; ++nt)
#pragma unroll
      for (int r = 0; r < 4; ++r) {
        float v = tanh_fast(acc[nt][r] + xwn[nt][r]);
        n0v[nt][r] = v;
        *(f16*)(nbuf + (dr + r) * 528 + (nc + nt * 16) * 2) = (f16)v;
      }
    barx();  // (1) n0 visible

    // ---- m1: n1 = relu(n0@Wh0[1] + b0[1]) + n0 ; prefetch Wh0[2]
    acc[0] = zero4; acc[1] = zero4;
    phase<8>(acc, nbuf + mn * 528,       bufA, wH0t + 262144,       bufA, q, mn);
    phase<8>(acc, nbuf + mn * 528 + 256, bufB, wH0t + 262144 + 256, bufB, q, mn);
    barx();  // (2) all n0 reads done (WAR)
#pragma unroll
    for (int nt = 0; nt < 2; ++nt) {
      float bv = *(const float*)(biasl + (nc + nt * 16) * 4);
#pragma unroll
      for (int r = 0; r < 4; ++r) {
        float v = fmaxf(acc[nt][r] + bv, 0.f) + n0v[nt][r];
        n1v[nt][r] = v;
        *(f16*)(nbuf + (dr + r) * 528 + (nc + nt * 16) * 2) = (f16)v;
      }
    }
    barx();  // (3) n1 visible

    // ---- m2: n2 = sigmoid(n1@Wh0[2] + b0[2]) + n0 ; h0' = 0.5(n1+n2) ; prefetch Win1
    acc[0] = zero4; acc[1] = zero4;
    phase<8>(acc, nbuf + mn * 528,       bufA, wI1t,       bufA, q, mn);
    phase<8>(acc, nbuf + mn * 528 + 256, bufB, wI1t + 256, bufB, q, mn);
#pragma unroll
    for (int nt = 0; nt < 2; ++nt) {
      float bv = *(const float*)(biasl + 1024 + (nc + nt * 16) * 4);
#pragma unroll
      for (int r = 0; r < 4; ++r) {
        float s = sigmoid_fast(acc[nt][r] + bv);
        float hv = 0.5f * (n1v[nt][r] + s + n0v[nt][r]);
        *(f16*)(hbuf0 + (dr + r) * 528 + (nc + nt * 16) * 2) = (f16)hv;
        if (last) out[2097152 + (size_t)(rb + dr + r) * 256 + nc + nt * 16] = hv;
      }
    }
    barx();  // (4) h0' visible

    // ---- m3+m4: n0' = tanh(h0'@Win1 + h1@Wh1[0] + b1[0]) ; prefetch Wh1[0], Wh1[1]
    acc[0] = zero4; acc[1] = zero4;
    phase<8>(acc, hbuf0 + mn * 528,       bufA, wH1t,       bufA, q, mn);
    phase<8>(acc, hbuf0 + mn * 528 + 256, bufB, wH1t + 256, bufB, q, mn);
    phase<8>(acc, hbuf1 + mn * 528,       bufA, wH1t + 131072,       bufA, q, mn);
    phase<8>(acc, hbuf1 + mn * 528 + 256, bufB, wH1t + 131072 + 256, bufB, q, mn);
#pragma unroll
    for (int nt = 0; nt < 2; ++nt) {
      float bv = *(const float*)(biasl + 2048 + (nc + nt * 16) * 4);
#pragma unroll
      for (int r = 0; r < 4; ++r) {
        float v = tanh_fast(acc[nt][r] + bv);
        n0v[nt][r] = v;
        *(f16*)(nbuf + (dr + r) * 528 + (nc + nt * 16) * 2) = (f16)v;
      }
    }
    barx();  // (5) n0' visible

    // ---- m5: n1' = relu(n0'@Wh1[1] + b1[1]) + n0' ; prefetch Wh1[2]
    acc[0] = zero4; acc[1] = zero4;
    phase<8>(acc, nbuf + mn * 528,       bufA, wH1t + 262144,       bufA, q, mn);
    phase<8>(acc, nbuf + mn * 528 + 256, bufB, wH1t + 262144 + 256, bufB, q, mn);
    barx();  // (6) all n0' reads done (WAR)
#pragma unroll
    for (int nt = 0; nt < 2; ++nt) {
      float bv = *(const float*)(biasl + 3072 + (nc + nt * 16) * 4);
#pragma unroll
      for (int r = 0; r < 4; ++r) {
        float v = fmaxf(acc[nt][r] + bv, 0.f) + n0v[nt][r];
        n1v[nt][r] = v;
        *(f16*)(nbuf + (dr + r) * 528 + (nc + nt * 16) * 2) = (f16)v;
      }
    }
    barx();  // (7) n1' visible

    // ---- m6: n2' = sigmoid(n1'@Wh1[2] + b1[2]) + n0' ; h1' = 0.5(n1'+n2') ;
    //          prefetch next step's Wh0[0]
    acc[0] = zero4; acc[1] = zero4;
    phase<8>(acc, nbuf + mn * 528,       bufA, wH0n,       bufA, q, mn);
    phase<8>(acc, nbuf + mn * 528 + 256, bufB, wH0n + 256, bufB, q, mn);
#pragma unroll
    for (int nt = 0; nt < 2; ++nt) {
      float bv = *(const float*)(biasl + 4096 + (nc + nt * 16) * 4);
#pragma unroll
      for (int r = 0; r < 4; ++r) {
        float s = sigmoid_fast(acc[nt][r] + bv);
        float hv = 0.5f * (n1v[nt][r] + s + n0v[nt][r]);
        *(f16*)(hbuf1 + (dr + r) * 528 + (nc + nt * 16) * 2) = (f16)hv;
        out[((size_t)(rb + dr + r) * Tt + t) * 256 + nc + nt * 16] = hv;
        if (last) out[2097152 + 32768 + (size_t)(rb + dr + r) * 256 + nc + nt * 16] = hv;
      }
    }
    // xw prefetch for next step (8 scalar loads; counted in m0's N=21)
#pragma unroll
    for (int nt = 0; nt < 2; ++nt)
#pragma unroll
      for (int r = 0; r < 4; ++r)
        xwn[nt][r] = xw[(size_t)tn * 32768 + (size_t)(rb + dr + r) * 256 + nc + nt * 16];
    sb();
    barx();  // (8) step end: h1' visible, nbuf reads done
  }
}

// ---------------- launch ----------------
extern "C" void kernel_launch(void* const* d_in, const int* in_sizes, int n_in,
                              void* d_out, int out_size, void* d_ws, size_t ws_size,
                              hipStream_t stream) {
  (void)in_sizes; (void)n_in; (void)out_size; (void)ws_size;
  const float* x      = (const float*)d_in[0];
  const float* hidden = (const float*)d_in[1];
  const float* Win0   = (const float*)d_in[2];
  const float* Wh0    = (const float*)d_in[3];
  const float* b0     = (const float*)d_in[4];
  const float* Win1   = (const float*)d_in[5];
  const float* Wh1    = (const float*)d_in[6];
  const float* b1     = (const float*)d_in[7];
  float* out = (float*)d_out;

  f16* ws    = (f16*)d_ws;
  f16* Win0T = ws;                       //  4,194,304 f16
  f16* Wh0T  = ws + 4194304;             // 12,582,912 f16
  f16* Win1T = ws + 16777216;            //  4,194,304 f16
  f16* Wh1T  = ws + 20971520;            // 12,582,912 f16
  float* xw  = (float*)(ws + 33554432);  //  2,097,152 f32

  transpose_cvt_kernel<<<dim3(32768), dim3(256), 0, stream>>>(
      Win0, Wh0, Win1, Wh1, Win0T, Wh0T, Win1T, Wh1T);
  xw_kernel<<<dim3(512), dim3(512), 0, stream>>>(x, Win0T, b0, xw);
  rnn_kernel<<<dim3(8), dim3(512), 0, stream>>>(
      hidden, Wh0T, b0, Win1T, Wh1T, b1, xw, out);
}

// Round 4
// 953.690 us; speedup vs baseline: 2.5096x; 1.4575x over previous
//
#include <hip/hip_runtime.h>

// CustomRNN: B=128, T=64, D=H=256, L=2, 3-node cell.
// Round 4: XOR-swizzled weight LDS layout (kills the 16-way bank conflicts
// measured in round 3: SQ_LDS_BANK_CONFLICT=13.8M), same async global_load_lds
// pipeline + lgkm-only barriers + manual vmcnt discipline. Faster transpose.
// 8 WGs x 16 batch rows, zero inter-WG sync.

typedef _Float16 f16;
typedef __attribute__((ext_vector_type(8))) _Float16 f16x8;
typedef __attribute__((ext_vector_type(4))) float f32x4;
typedef __attribute__((ext_vector_type(4))) float float4v;

#define Tt 64

// ---------------- helpers ----------------
__device__ __forceinline__ void sb() { __builtin_amdgcn_sched_barrier(0); }

template <int N>
__device__ __forceinline__ void waitvm() {
  // s_waitcnt vmcnt(N), lgkm=15 (no wait), exp=7 (no wait); gfx9 encoding
  __builtin_amdgcn_s_waitcnt(0x0F70 | (N & 15) | ((N >> 4) << 14));
}
__device__ __forceinline__ void waitlgkm0() { __builtin_amdgcn_s_waitcnt(0xC07F); }

__device__ __forceinline__ void barx() {
  // barrier that drains LDS ops only -- weight DMAs (vmcnt) stay in flight
  asm volatile("s_waitcnt lgkmcnt(0)\n\ts_barrier" ::: "memory");
}

__device__ __forceinline__ void dma16(const void* g, void* l) {
  __builtin_amdgcn_global_load_lds(
      (const __attribute__((address_space(1))) unsigned int*)g,
      (__attribute__((address_space(3))) unsigned int*)l, 16, 0, 0);
}

__device__ __forceinline__ float tanh_fast(float x) {
  float xc = fminf(fmaxf(x, -15.f), 15.f);
  float e = __expf(2.f * xc);
  return (e - 1.f) / (e + 1.f);
}
__device__ __forceinline__ float sigmoid_fast(float x) { return 1.f / (1.f + __expf(-x)); }

// ---------------- transpose+convert: [k][n] f32 -> [n][k] f16 ----------------
// Block = 32 output rows (n) x full K=256. Grid = 512 matrices x 8 n-tiles.
__global__ __launch_bounds__(256) void transpose_cvt_kernel(
    const float* __restrict__ Win0, const float* __restrict__ Wh0,
    const float* __restrict__ Win1, const float* __restrict__ Wh1,
    f16* __restrict__ Win0T, f16* __restrict__ Wh0T,
    f16* __restrict__ Win1T, f16* __restrict__ Wh1T) {
  __shared__ float tile[256 * 33];   // stride 33 dwords: conflict-free both sides
  const int bid = blockIdx.x;
  const int mat = bid >> 3, n0 = (bid & 7) << 5;
  const float* src; f16* dst;
  if (mat < 64)       { src = Win0 + (size_t)mat * 65536;         dst = Win0T + (size_t)mat * 65536; }
  else if (mat < 256) { src = Wh0  + (size_t)(mat - 64) * 65536;  dst = Wh0T  + (size_t)(mat - 64) * 65536; }
  else if (mat < 320) { src = Win1 + (size_t)(mat - 256) * 65536; dst = Win1T + (size_t)(mat - 256) * 65536; }
  else                { src = Wh1  + (size_t)(mat - 320) * 65536; dst = Wh1T  + (size_t)(mat - 320) * 65536; }
  const int tid = threadIdx.x;
  const int c2 = tid & 15, kl = tid >> 4;
#pragma unroll
  for (int p = 0; p < 16; ++p) {
    const int k = kl + p * 16;
    float2 v = *(const float2*)(src + k * 256 + n0 + c2 * 2);
    tile[k * 33 + c2 * 2]     = v.x;
    tile[k * 33 + c2 * 2 + 1] = v.y;
  }
  __syncthreads();
  const int n = tid & 7, c = tid >> 3;   // c: 16B chunk 0..31 along k
#pragma unroll
  for (int it = 0; it < 4; ++it) {
    const int nn = n + it * 8;
    f16x8 vv;
#pragma unroll
    for (int i = 0; i < 8; ++i) vv[i] = (f16)tile[(c * 8 + i) * 33 + nn];
    *(f16x8*)((char*)dst + (size_t)(n0 + nn) * 512 + c * 16) = vv;
  }
}

// ---------------- xw precompute: xw[t,b,h] = x[b,t,:]@Win0[t] + b0[t,0,h] ----------------
__global__ __launch_bounds__(512, 2) void xw_kernel(
    const float* __restrict__ x, const f16* __restrict__ Win0T,
    const float* __restrict__ b0, float* __restrict__ xw) {
  const int t = blockIdx.x >> 3, bb = blockIdx.x & 7;
  const int rb = bb << 4;
  const int tid = threadIdx.x, lane = tid & 63, w = tid >> 6;
  const int q = lane >> 4, mn = lane & 15;
  const int nc = w * 32 + mn, dr = q * 4;
  const f16* wt = Win0T + (size_t)t * 65536;
  const float4v* xr = (const float4v*)(x + ((size_t)(rb + mn) * Tt + t) * 256);
  f32x4 acc[2] = {{0.f,0.f,0.f,0.f},{0.f,0.f,0.f,0.f}};
#pragma unroll
  for (int kt = 0; kt < 8; ++kt) {
    const int k0 = kt * 32 + q * 8;
    float4v x0 = xr[k0 / 4], x1 = xr[k0 / 4 + 1];
    f16x8 a = {(f16)x0.x, (f16)x0.y, (f16)x0.z, (f16)x0.w,
               (f16)x1.x, (f16)x1.y, (f16)x1.z, (f16)x1.w};
#pragma unroll
    for (int nt = 0; nt < 2; ++nt) {
      f16x8 b = *(const f16x8*)(wt + (size_t)(nc + nt * 16) * 256 + k0);
      acc[nt] = __builtin_amdgcn_mfma_f32_16x16x32_f16(a, b, acc[nt], 0, 0, 0);
    }
  }
#pragma unroll
  for (int nt = 0; nt < 2; ++nt) {
    const float bv = b0[(size_t)t * 768 + nc + nt * 16];
#pragma unroll
    for (int r = 0; r < 4; ++r)
      xw[(size_t)t * 32768 + (size_t)(rb + dr + r) * 256 + nc + nt * 16] = acc[nt][r] + bv;
  }
}

// ---------------- one matmul K-half phase ----------------
// Swizzled LDS weight layout: logical (row n, 16B chunk c) lives at physical
// chunk c^(n&15). DMA gather absorbs the swizzle via off[]; reads via bo[].
template <int NW>
__device__ __forceinline__ void phase(f32x4 (&acc)[2], const char* arow, const char* wb,
                                      const int (&bo)[4], const char* gnext, char* lnext,
                                      const int (&off)[8], int q) {
  waitvm<NW>();   // our half's DMA has landed
  sb();
  f16x8 a[4], b[8];
#pragma unroll
  for (int kt = 0; kt < 4; ++kt) {
    a[kt]         = *(const f16x8*)(arow + kt * 64 + q * 16);
    b[kt * 2]     = *(const f16x8*)(wb + bo[kt]);
    b[kt * 2 + 1] = *(const f16x8*)(wb + bo[kt] + 4096);
  }
  sb();
  waitlgkm0();            // reads executed -> safe to overwrite buffer
#pragma unroll
  for (int d = 0; d < 8; ++d) dma16(gnext + off[d], lnext + d * 1024);
  sb();
#pragma unroll
  for (int kt = 0; kt < 4; ++kt) {
    acc[0] = __builtin_amdgcn_mfma_f32_16x16x32_f16(a[kt], b[kt * 2],     acc[0], 0, 0, 0);
    acc[1] = __builtin_amdgcn_mfma_f32_16x16x32_f16(a[kt], b[kt * 2 + 1], acc[1], 0, 0, 0);
  }
}

// ---------------- recurrent kernel: 8 WGs x 16 batch rows ----------------
__global__ __launch_bounds__(512, 1) void rnn_kernel(
    const float* __restrict__ hidden,
    const f16* __restrict__ Wh0T, const float* __restrict__ b0,
    const f16* __restrict__ Win1T, const f16* __restrict__ Wh1T, const float* __restrict__ b1,
    const float* __restrict__ xw, float* __restrict__ out) {
  // LDS: [0,128K) per-wave weight slices (bufA 8K + bufB 8K);
  //      hbuf0/hbuf1/nbuf (16 x 264 f16 = 8448B each); bias 5KB
  __shared__ __align__(16) char smem[161536];
  char* wlds  = smem;
  char* hbuf0 = smem + 131072;
  char* hbuf1 = smem + 139520;
  char* nbuf  = smem + 147968;
  char* biasl = smem + 156416;

  const int tid = threadIdx.x;
  const int lane = tid & 63;
  const int w = tid >> 6;
  const int q = lane >> 4;
  const int mn = lane & 15;
  const int rb = blockIdx.x << 4;
  const int nc = w * 32 + mn;
  const int dr = q * 4;

  // per-lane swizzled offsets: DMA gather (off) and B-fragment reads (bo)
  int off[8], bo[4];
#pragma unroll
  for (int d = 0; d < 8; ++d) {
    const int row = 4 * d + q;
    off[d] = row * 512 + ((mn ^ (row & 15)) << 4);
  }
#pragma unroll
  for (int kt = 0; kt < 4; ++kt)
    bo[kt] = mn * 256 + (((kt * 4 + q) ^ mn) << 4);

  // hidden f32 -> f16 into hbuf0/hbuf1
  for (int i = tid; i < 16 * 256; i += 512) {
    const int m = i >> 8, n = i & 255;
    *(f16*)(hbuf0 + m * 528 + n * 2) = (f16)hidden[(size_t)(rb + m) * 256 + n];
    *(f16*)(hbuf1 + m * 528 + n * 2) = (f16)hidden[(size_t)(128 + rb + m) * 256 + n];
  }
  barx();

  char* bufA = wlds + w * 16384;
  char* bufB = bufA + 8192;
  const char* Wh0b  = (const char*)Wh0T;
  const char* Win1b = (const char*)Win1T;
  const char* Wh1b  = (const char*)Wh1T;
  const char* b0c = (const char*)b0;
  const char* b1c = (const char*)b1;

  // prelude: DMA t=0 m0 weights (Wh0[0][0]) halves (all A then all B!)
  {
    const char* gw = Wh0b + w * 16384;
#pragma unroll
    for (int d = 0; d < 8; ++d) dma16(gw + off[d], bufA + d * 1024);
#pragma unroll
    for (int d = 0; d < 8; ++d) dma16(gw + 256 + off[d], bufB + d * 1024);
    sb();
  }
  float xwn[2][4];
#pragma unroll
  for (int nt = 0; nt < 2; ++nt)
#pragma unroll
    for (int r = 0; r < 4; ++r)
      xwn[nt][r] = xw[(size_t)(rb + dr + r) * 256 + nc + nt * 16];
  sb();

  float n0v[2][4], n1v[2][4];
  const f32x4 zero4 = {0.f, 0.f, 0.f, 0.f};

#pragma unroll 1
  for (int t = 0; t < Tt; ++t) {
    const int tn = (t < Tt - 1) ? t + 1 : t;
    const bool last = (t == Tt - 1);
    const char* wH0t = Wh0b + (size_t)t * 393216 + w * 16384;
    const char* wI1t = Win1b + (size_t)t * 131072 + w * 16384;
    const char* wH1t = Wh1b + (size_t)t * 393216 + w * 16384;
    const char* wH0n = Wh0b + (size_t)tn * 393216 + w * 16384;

    // step-start: bias DMA (b0[t][1..2] -> idx0,1 ; b1[t][0..2] -> idx2..4)
    {
      const char* g0 = b0c + (size_t)t * 3072 + 1024 + lane * 16;
      dma16(g0, biasl);
      dma16(g0 + 1024, biasl + 1024);
      const char* g1 = b1c + (size_t)t * 3072 + lane * 16;
      dma16(g1, biasl + 2048);
      dma16(g1 + 1024, biasl + 3072);
      dma16(g1 + 2048, biasl + 4096);
      sb();
    }

    f32x4 acc[2];

    // ---- m0: n0 = tanh(h0@Wh0[0] + xw) ; prefetch Wh0[1]
    acc[0] = zero4; acc[1] = zero4;
    phase<21>(acc, hbuf0 + mn * 528,       bufA, bo, wH0t + 131072,       bufA, off, q);
    phase<21>(acc, hbuf0 + mn * 528 + 256, bufB, bo, wH0t + 131072 + 256, bufB, off, q);
#pragma unroll
    for (int nt = 0; nt < 2; ++nt)
#pragma unroll
      for (int r = 0; r < 4; ++r) {
        float v = tanh_fast(acc[nt][r] + xwn[nt][r]);
        n0v[nt][r] = v;
        *(f16*)(nbuf + (dr + r) * 528 + (nc + nt * 16) * 2) = (f16)v;
      }
    barx();  // (1) n0 visible

    // ---- m1: n1 = relu(n0@Wh0[1] + b0[1]) + n0 ; prefetch Wh0[2]
    acc[0] = zero4; acc[1] = zero4;
    phase<8>(acc, nbuf + mn * 528,       bufA, bo, wH0t + 262144,       bufA, off, q);
    phase<8>(acc, nbuf + mn * 528 + 256, bufB, bo, wH0t + 262144 + 256, bufB, off, q);
    barx();  // (2) all n0 reads done (WAR)
#pragma unroll
    for (int nt = 0; nt < 2; ++nt) {
      float bv = *(const float*)(biasl + (nc + nt * 16) * 4);
#pragma unroll
      for (int r = 0; r < 4; ++r) {
        float v = fmaxf(acc[nt][r] + bv, 0.f) + n0v[nt][r];
        n1v[nt][r] = v;
        *(f16*)(nbuf + (dr + r) * 528 + (nc + nt * 16) * 2) = (f16)v;
      }
    }
    barx();  // (3) n1 visible

    // ---- m2: n2 = sigmoid(n1@Wh0[2] + b0[2]) + n0 ; h0' = 0.5(n1+n2) ; prefetch Win1
    acc[0] = zero4; acc[1] = zero4;
    phase<8>(acc, nbuf + mn * 528,       bufA, bo, wI1t,       bufA, off, q);
    phase<8>(acc, nbuf + mn * 528 + 256, bufB, bo, wI1t + 256, bufB, off, q);
#pragma unroll
    for (int nt = 0; nt < 2; ++nt) {
      float bv = *(const float*)(biasl + 1024 + (nc + nt * 16) * 4);
#pragma unroll
      for (int r = 0; r < 4; ++r) {
        float s = sigmoid_fast(acc[nt][r] + bv);
        float hv = 0.5f * (n1v[nt][r] + s + n0v[nt][r]);
        *(f16*)(hbuf0 + (dr + r) * 528 + (nc + nt * 16) * 2) = (f16)hv;
        if (last) out[2097152 + (size_t)(rb + dr + r) * 256 + nc + nt * 16] = hv;
      }
    }
    barx();  // (4) h0' visible

    // ---- m3+m4: n0' = tanh(h0'@Win1 + h1@Wh1[0] + b1[0]) ; prefetch Wh1[0], Wh1[1]
    acc[0] = zero4; acc[1] = zero4;
    phase<8>(acc, hbuf0 + mn * 528,       bufA, bo, wH1t,       bufA, off, q);
    phase<8>(acc, hbuf0 + mn * 528 + 256, bufB, bo, wH1t + 256, bufB, off, q);
    phase<8>(acc, hbuf1 + mn * 528,       bufA, bo, wH1t + 131072,       bufA, off, q);
    phase<8>(acc, hbuf1 + mn * 528 + 256, bufB, bo, wH1t + 131072 + 256, bufB, off, q);
#pragma unroll
    for (int nt = 0; nt < 2; ++nt) {
      float bv = *(const float*)(biasl + 2048 + (nc + nt * 16) * 4);
#pragma unroll
      for (int r = 0; r < 4; ++r) {
        float v = tanh_fast(acc[nt][r] + bv);
        n0v[nt][r] = v;
        *(f16*)(nbuf + (dr + r) * 528 + (nc + nt * 16) * 2) = (f16)v;
      }
    }
    barx();  // (5) n0' visible

    // ---- m5: n1' = relu(n0'@Wh1[1] + b1[1]) + n0' ; prefetch Wh1[2]
    acc[0] = zero4; acc[1] = zero4;
    phase<8>(acc, nbuf + mn * 528,       bufA, bo, wH1t + 262144,       bufA, off, q);
    phase<8>(acc, nbuf + mn * 528 + 256, bufB, bo, wH1t + 262144 + 256, bufB, off, q);
    barx();  // (6) all n0' reads done (WAR)
#pragma unroll
    for (int nt = 0; nt < 2; ++nt) {
      float bv = *(const float*)(biasl + 3072 + (nc + nt * 16) * 4);
#pragma unroll
      for (int r = 0; r < 4; ++r) {
        float v = fmaxf(acc[nt][r] + bv, 0.f) + n0v[nt][r];
        n1v[nt][r] = v;
        *(f16*)(nbuf + (dr + r) * 528 + (nc + nt * 16) * 2) = (f16)v;
      }
    }
    barx();  // (7) n1' visible

    // ---- m6: n2' = sigmoid(n1'@Wh1[2] + b1[2]) + n0' ; h1' = 0.5(n1'+n2') ;
    //          prefetch next step's Wh0[0]
    acc[0] = zero4; acc[1] = zero4;
    phase<8>(acc, nbuf + mn * 528,       bufA, bo, wH0n,       bufA, off, q);
    phase<8>(acc, nbuf + mn * 528 + 256, bufB, bo, wH0n + 256, bufB, off, q);
#pragma unroll
    for (int nt = 0; nt < 2; ++nt) {
      float bv = *(const float*)(biasl + 4096 + (nc + nt * 16) * 4);
#pragma unroll
      for (int r = 0; r < 4; ++r) {
        float s = sigmoid_fast(acc[nt][r] + bv);
        float hv = 0.5f * (n1v[nt][r] + s + n0v[nt][r]);
        *(f16*)(hbuf1 + (dr + r) * 528 + (nc + nt * 16) * 2) = (f16)hv;
        out[((size_t)(rb + dr + r) * Tt + t) * 256 + nc + nt * 16] = hv;
        if (last) out[2097152 + 32768 + (size_t)(rb + dr + r) * 256 + nc + nt * 16] = hv;
      }
    }
    // xw prefetch for next step (8 scalar loads; counted in m0's N=21)
#pragma unroll
    for (int nt = 0; nt < 2; ++nt)
#pragma unroll
      for (int r = 0; r < 4; ++r)
        xwn[nt][r] = xw[(size_t)tn * 32768 + (size_t)(rb + dr + r) * 256 + nc + nt * 16];
    sb();
    barx();  // (8) step end: h1' visible, nbuf reads done
  }
}

// ---------------- launch ----------------
extern "C" void kernel_launch(void* const* d_in, const int* in_sizes, int n_in,
                              void* d_out, int out_size, void* d_ws, size_t ws_size,
                              hipStream_t stream) {
  (void)in_sizes; (void)n_in; (void)out_size; (void)ws_size;
  const float* x      = (const float*)d_in[0];
  const float* hidden = (const float*)d_in[1];
  const float* Win0   = (const float*)d_in[2];
  const float* Wh0    = (const float*)d_in[3];
  const float* b0     = (const float*)d_in[4];
  const float* Win1   = (const float*)d_in[5];
  const float* Wh1    = (const float*)d_in[6];
  const float* b1     = (const float*)d_in[7];
  float* out = (float*)d_out;

  f16* ws    = (f16*)d_ws;
  f16* Win0T = ws;                       //  4,194,304 f16
  f16* Wh0T  = ws + 4194304;             // 12,582,912 f16
  f16* Win1T = ws + 16777216;            //  4,194,304 f16
  f16* Wh1T  = ws + 20971520;            // 12,582,912 f16
  float* xw  = (float*)(ws + 33554432);  //  2,097,152 f32

  transpose_cvt_kernel<<<dim3(4096), dim3(256), 0, stream>>>(
      Win0, Wh0, Win1, Wh1, Win0T, Wh0T, Win1T, Wh1T);
  xw_kernel<<<dim3(512), dim3(512), 0, stream>>>(x, Win0T, b0, xw);
  rnn_kernel<<<dim3(8), dim3(512), 0, stream>>>(
      hidden, Wh0T, b0, Win1T, Wh1T, b1, xw, out);
}

// Round 5
// 798.294 us; speedup vs baseline: 2.9981x; 1.1947x over previous
//
#include <hip/hip_runtime.h>

// CustomRNN: B=128, T=64, D=H=256, L=2, 3-node cell.
// Round 5: LAYER PIPELINING. Round 4 was per-CU weight-ingest bound
// (56.6 MB/CU at ~30 B/cyc). Split layers across CU pairs: 8 producer WGs
// (layer 0, 24 MB/CU) + 8 consumer WGs (layer 1, 32 MB/CU), handoff of
// h0'(t) via global hseq + per-(g,t) release/acquire flags (magic-tagged,
// 0xAA-poison-proof). Same XOR-swizzled LDS weight DMA pipeline as round 4.

typedef _Float16 f16;
typedef __attribute__((ext_vector_type(8))) _Float16 f16x8;
typedef __attribute__((ext_vector_type(4))) float f32x4;
typedef __attribute__((ext_vector_type(4))) float float4v;

#define Tt 64
#define FLAG_MAGIC 0x52570000

// ---------------- helpers ----------------
__device__ __forceinline__ void sb() { __builtin_amdgcn_sched_barrier(0); }

template <int N>
__device__ __forceinline__ void waitvm() {
  // s_waitcnt vmcnt(N), lgkm=15 (no wait), exp=7 (no wait); gfx9 encoding
  __builtin_amdgcn_s_waitcnt(0x0F70 | (N & 15) | ((N >> 4) << 14));
}
__device__ __forceinline__ void waitlgkm0() { __builtin_amdgcn_s_waitcnt(0xC07F); }

__device__ __forceinline__ void barx() {
  // barrier draining LDS ops only -- weight DMAs (vmcnt) stay in flight
  asm volatile("s_waitcnt lgkmcnt(0)\n\ts_barrier" ::: "memory");
}

__device__ __forceinline__ void dma16(const void* g, void* l) {
  __builtin_amdgcn_global_load_lds(
      (const __attribute__((address_space(1))) unsigned int*)g,
      (__attribute__((address_space(3))) unsigned int*)l, 16, 0, 0);
}

__device__ __forceinline__ float tanh_fast(float x) {
  float xc = fminf(fmaxf(x, -15.f), 15.f);
  float e = __expf(2.f * xc);
  return (e - 1.f) / (e + 1.f);
}
__device__ __forceinline__ float sigmoid_fast(float x) { return 1.f / (1.f + __expf(-x)); }

// ---------------- transpose+convert: [k][n] f32 -> [n][k] f16 ----------------
// 448 matrices: 192 Wh0 + 64 Win1 + 192 Wh1 (Win0 consumed raw by xw_kernel)
__global__ __launch_bounds__(256) void transpose_cvt_kernel(
    const float* __restrict__ Wh0, const float* __restrict__ Win1,
    const float* __restrict__ Wh1,
    f16* __restrict__ Wh0T, f16* __restrict__ Win1T, f16* __restrict__ Wh1T) {
  __shared__ float tile[256 * 33];
  const int bid = blockIdx.x;
  const int mat = bid >> 3, n0 = (bid & 7) << 5;
  const float* src; f16* dst;
  if (mat < 192)      { src = Wh0  + (size_t)mat * 65536;         dst = Wh0T  + (size_t)mat * 65536; }
  else if (mat < 256) { src = Win1 + (size_t)(mat - 192) * 65536; dst = Win1T + (size_t)(mat - 192) * 65536; }
  else                { src = Wh1  + (size_t)(mat - 256) * 65536; dst = Wh1T  + (size_t)(mat - 256) * 65536; }
  const int tid = threadIdx.x;
  const int c2 = tid & 15, kl = tid >> 4;
#pragma unroll
  for (int p = 0; p < 16; ++p) {
    const int k = kl + p * 16;
    float2 v = *(const float2*)(src + k * 256 + n0 + c2 * 2);
    tile[k * 33 + c2 * 2]     = v.x;
    tile[k * 33 + c2 * 2 + 1] = v.y;
  }
  __syncthreads();
  const int n = tid & 7, c = tid >> 3;
#pragma unroll
  for (int it = 0; it < 4; ++it) {
    const int nn = n + it * 8;
    f16x8 vv;
#pragma unroll
    for (int i = 0; i < 8; ++i) vv[i] = (f16)tile[(c * 8 + i) * 33 + nn];
    *(f16x8*)((char*)dst + (size_t)(n0 + nn) * 512 + c * 16) = vv;
  }
}

// ---------------- xw precompute: xw[t,b,h] = x[b,t,:]@Win0[t] + b0[t,0,h] ----
// Reads Win0 raw f32 (strided) -- L2 absorbs repeats across the 8 batch tiles.
__global__ __launch_bounds__(512, 2) void xw_kernel(
    const float* __restrict__ x, const float* __restrict__ Win0,
    const float* __restrict__ b0, float* __restrict__ xw) {
  const int t = blockIdx.x >> 3, bb = blockIdx.x & 7;
  const int rb = bb << 4;
  const int tid = threadIdx.x, lane = tid & 63, w = tid >> 6;
  const int q = lane >> 4, mn = lane & 15;
  const int nc = w * 32 + mn, dr = q * 4;
  const float* wt = Win0 + (size_t)t * 65536;
  const float4v* xr = (const float4v*)(x + ((size_t)(rb + mn) * Tt + t) * 256);
  f32x4 acc[2] = {{0.f,0.f,0.f,0.f},{0.f,0.f,0.f,0.f}};
#pragma unroll
  for (int kt = 0; kt < 8; ++kt) {
    const int k0 = kt * 32 + q * 8;
    float4v x0 = xr[k0 / 4], x1 = xr[k0 / 4 + 1];
    f16x8 a = {(f16)x0.x, (f16)x0.y, (f16)x0.z, (f16)x0.w,
               (f16)x1.x, (f16)x1.y, (f16)x1.z, (f16)x1.w};
#pragma unroll
    for (int nt = 0; nt < 2; ++nt) {
      f16x8 b;
#pragma unroll
      for (int j = 0; j < 8; ++j) b[j] = (f16)wt[(size_t)(k0 + j) * 256 + nc + nt * 16];
      acc[nt] = __builtin_amdgcn_mfma_f32_16x16x32_f16(a, b, acc[nt], 0, 0, 0);
    }
  }
#pragma unroll
  for (int nt = 0; nt < 2; ++nt) {
    const float bv = b0[(size_t)t * 768 + nc + nt * 16];
#pragma unroll
    for (int r = 0; r < 4; ++r)
      xw[(size_t)t * 32768 + (size_t)(rb + dr + r) * 256 + nc + nt * 16] = acc[nt][r] + bv;
  }
}

// ---------------- matmul K-half phase (A from LDS) ----------------
template <int NW, bool DMA>
__device__ __forceinline__ void phase(f32x4 (&acc)[2], const char* arow, const char* wb,
                                      const int (&bo)[4], const char* gnext, char* lnext,
                                      const int (&off)[8], int q) {
  waitvm<NW>();
  sb();
  f16x8 a[4], b[8];
#pragma unroll
  for (int kt = 0; kt < 4; ++kt) {
    a[kt]         = *(const f16x8*)(arow + kt * 64 + q * 16);
    b[kt * 2]     = *(const f16x8*)(wb + bo[kt]);
    b[kt * 2 + 1] = *(const f16x8*)(wb + bo[kt] + 4096);
  }
  sb();
  waitlgkm0();
  if (DMA) {
#pragma unroll
    for (int d = 0; d < 8; ++d) dma16(gnext + off[d], lnext + d * 1024);
  }
  sb();
#pragma unroll
  for (int kt = 0; kt < 4; ++kt) {
    acc[0] = __builtin_amdgcn_mfma_f32_16x16x32_f16(a[kt], b[kt * 2],     acc[0], 0, 0, 0);
    acc[1] = __builtin_amdgcn_mfma_f32_16x16x32_f16(a[kt], b[kt * 2 + 1], acc[1], 0, 0, 0);
  }
}

// ---------------- matmul K-half phase (A from registers) ----------------
template <int NW>
__device__ __forceinline__ void phaseRA(f32x4 (&acc)[2], const f16x8* af, const char* wb,
                                        const int (&bo)[4], const char* gnext, char* lnext,
                                        const int (&off)[8]) {
  waitvm<NW>();
  sb();
  f16x8 b[8];
#pragma unroll
  for (int kt = 0; kt < 4; ++kt) {
    b[kt * 2]     = *(const f16x8*)(wb + bo[kt]);
    b[kt * 2 + 1] = *(const f16x8*)(wb + bo[kt] + 4096);
  }
  sb();
  waitlgkm0();
#pragma unroll
  for (int d = 0; d < 8; ++d) dma16(gnext + off[d], lnext + d * 1024);
  sb();
#pragma unroll
  for (int kt = 0; kt < 4; ++kt) {
    acc[0] = __builtin_amdgcn_mfma_f32_16x16x32_f16(af[kt], b[kt * 2],     acc[0], 0, 0, 0);
    acc[1] = __builtin_amdgcn_mfma_f32_16x16x32_f16(af[kt], b[kt * 2 + 1], acc[1], 0, 0, 0);
  }
}

// ---------------- recurrent kernel: 16 WGs (8 L0 + 8 L1), 16 rows each ------
__global__ __launch_bounds__(512, 1) void rnn_kernel(
    const float* __restrict__ hidden,
    const f16* __restrict__ Wh0T, const float* __restrict__ b0,
    const f16* __restrict__ Win1T, const f16* __restrict__ Wh1T, const float* __restrict__ b1,
    const float* __restrict__ xw, f16* __restrict__ hseq, int* __restrict__ flags,
    float* __restrict__ out) {
  __shared__ __align__(16) char smem[147968];
  char* wlds = smem;                 // 8 waves x 16 KB
  char* abuf = smem + 131072;        // recurrent h (hbuf0 for L0 / hbuf1 for L1)
  char* nbuf = smem + 139520;

  const int tid = threadIdx.x;
  const int lane = tid & 63;
  const int w = tid >> 6;
  const int q = lane >> 4;
  const int mn = lane & 15;
  const bool isL0 = blockIdx.x < 8;
  const int g = blockIdx.x & 7;
  const int rb = g << 4;
  const int nc = w * 32 + mn;
  const int dr = q * 4;
  const int wslice = w * 16384;

  int off[8], bo[4];
#pragma unroll
  for (int d = 0; d < 8; ++d) {
    const int row = 4 * d + q;
    off[d] = row * 512 + ((mn ^ (row & 15)) << 4);
  }
#pragma unroll
  for (int kt = 0; kt < 4; ++kt)
    bo[kt] = mn * 256 + (((kt * 4 + q) ^ mn) << 4);

  // init recurrent state (layer-appropriate half of hidden)
  const float* hsrc = hidden + (isL0 ? 0 : 32768) + (size_t)rb * 256;
  for (int i = tid; i < 16 * 256; i += 512) {
    const int m = i >> 8, n = i & 255;
    *(f16*)(abuf + m * 528 + n * 2) = (f16)hsrc[m * 256 + n];
  }

  char* bufA = wlds + wslice;
  char* bufB = bufA + 8192;
  const f32x4 zero4 = {0.f, 0.f, 0.f, 0.f};
  float n0v[2][4], n1v[2][4];

  if (isL0) {
    // =================== LAYER-0 PRODUCER ===================
    const char* WB = (const char*)Wh0T;   // [t][3][256][256] f16 (transposed)
    { // prelude: DMA Wh0[0](t=0) halves
      const char* gw = WB + wslice;
#pragma unroll
      for (int d = 0; d < 8; ++d) dma16(gw + off[d], bufA + d * 1024);
#pragma unroll
      for (int d = 0; d < 8; ++d) dma16(gw + 256 + off[d], bufB + d * 1024);
      sb();
    }
    barx();

#pragma unroll 1
    for (int t = 0; t < Tt; ++t) {
      const int tn = (t < Tt - 1) ? t + 1 : t;
      const bool last = (t == Tt - 1);
      const char* wt  = WB + (size_t)t * 393216 + wslice;
      const char* wtn = WB + (size_t)tn * 393216 + wslice;

      // loop top: xw(t) [8 loads] + bias [4 loads]
      float xwv[2][4];
#pragma unroll
      for (int nt = 0; nt < 2; ++nt)
#pragma unroll
        for (int r = 0; r < 4; ++r)
          xwv[nt][r] = xw[(size_t)t * 32768 + (size_t)(rb + dr + r) * 256 + nc + nt * 16];
      const float bv1a = b0[(size_t)t * 768 + 256 + nc], bv1b = b0[(size_t)t * 768 + 256 + nc + 16];
      const float bv2a = b0[(size_t)t * 768 + 512 + nc], bv2b = b0[(size_t)t * 768 + 512 + nc + 16];
      sb();

      f32x4 acc[2];
      // ---- m0: n0 = tanh(h0@Wh0[0] + xw) ; prefetch Wh0[1]
      acc[0] = zero4; acc[1] = zero4;
      phase<20, true>(acc, abuf + mn * 528,       bufA, bo, wt + 131072,       bufA, off, q);
      phase<20, true>(acc, abuf + mn * 528 + 256, bufB, bo, wt + 131072 + 256, bufB, off, q);
      waitvm<20>();   // xw landed (leaves bias4 + Wh0[1] dmas)
      sb();
#pragma unroll
      for (int nt = 0; nt < 2; ++nt)
#pragma unroll
        for (int r = 0; r < 4; ++r) {
          float v = tanh_fast(acc[nt][r] + xwv[nt][r]);
          n0v[nt][r] = v;
          *(f16*)(nbuf + (dr + r) * 528 + (nc + nt * 16) * 2) = (f16)v;
        }
      barx();  // (1) n0 visible

      // ---- m1: n1 = relu(n0@Wh0[1] + b0[1]) + n0 ; prefetch Wh0[2]
      acc[0] = zero4; acc[1] = zero4;
      phase<8, true>(acc, nbuf + mn * 528,       bufA, bo, wt + 262144,       bufA, off, q);
      phase<8, true>(acc, nbuf + mn * 528 + 256, bufB, bo, wt + 262144 + 256, bufB, off, q);
      barx();  // (2) n0 reads done (WAR)
#pragma unroll
      for (int nt = 0; nt < 2; ++nt) {
        const float bv = nt ? bv1b : bv1a;
#pragma unroll
        for (int r = 0; r < 4; ++r) {
          float v = fmaxf(acc[nt][r] + bv, 0.f) + n0v[nt][r];
          n1v[nt][r] = v;
          *(f16*)(nbuf + (dr + r) * 528 + (nc + nt * 16) * 2) = (f16)v;
        }
      }
      barx();  // (3) n1 visible

      // ---- m2: n2 = sigmoid(n1@Wh0[2] + b0[2]) + n0 ; h0' = 0.5(n1+n2); no DMA
      acc[0] = zero4; acc[1] = zero4;
      phase<8, false>(acc, nbuf + mn * 528,       bufA, bo, wt, bufA, off, q);
      phase<0, false>(acc, nbuf + mn * 528 + 256, bufB, bo, wt, bufB, off, q);
      // epi: write h0' to abuf (LDS) + hseq (global), publish flag
#pragma unroll
      for (int nt = 0; nt < 2; ++nt) {
        const float bv = nt ? bv2b : bv2a;
#pragma unroll
        for (int r = 0; r < 4; ++r) {
          float s = sigmoid_fast(acc[nt][r] + bv);
          float hv = 0.5f * (n1v[nt][r] + s + n0v[nt][r]);
          f16 h16 = (f16)hv;
          *(f16*)(abuf + (dr + r) * 528 + (nc + nt * 16) * 2) = h16;
          hseq[((size_t)(g * 64 + t)) * 4096 + (dr + r) * 256 + nc + nt * 16] = h16;
          if (last) out[2097152 + (size_t)(rb + dr + r) * 256 + nc + nt * 16] = hv;
        }
      }
      waitvm<0>();          // all hseq stores of this wave complete
      __threadfence();      // device-scope release of data
      __syncthreads();      // all waves' stores complete
      if (tid == 0) {
        __hip_atomic_store(&flags[g * 64 + t], FLAG_MAGIC | (t + 1),
                           __ATOMIC_RELEASE, __HIP_MEMORY_SCOPE_AGENT);
      }
      sb();
      // prefetch next step's Wh0[0] halves
      {
        const char* gw = wtn;
#pragma unroll
        for (int d = 0; d < 8; ++d) dma16(gw + off[d], bufA + d * 1024);
#pragma unroll
        for (int d = 0; d < 8; ++d) dma16(gw + 256 + off[d], bufB + d * 1024);
        sb();
      }
    }
  } else {
    // =================== LAYER-1 CONSUMER ===================
    const char* WI = (const char*)Win1T;  // [t][256][256]
    const char* WH = (const char*)Wh1T;   // [t][3][256][256]
    const f16* hsg = hseq + (size_t)g * 64 * 4096;
    { // prelude: DMA Wh1[0](t=0) halves
      const char* gw = WH + wslice;
#pragma unroll
      for (int d = 0; d < 8; ++d) dma16(gw + off[d], bufA + d * 1024);
#pragma unroll
      for (int d = 0; d < 8; ++d) dma16(gw + 256 + off[d], bufB + d * 1024);
      sb();
    }
    barx();

#pragma unroll 1
    for (int t = 0; t < Tt; ++t) {
      const int tn = (t < Tt - 1) ? t + 1 : t;
      const bool last = (t == Tt - 1);
      const char* wit = WI + (size_t)t * 131072 + wslice;
      const char* wht = WH + (size_t)t * 393216 + wslice;
      const char* whn = WH + (size_t)tn * 393216 + wslice;

      // poll producer flag (acquire; drains vmcnt implicitly)
      {
        const int want = FLAG_MAGIC | (t + 1);
        while (__hip_atomic_load(&flags[g * 64 + t], __ATOMIC_ACQUIRE,
                                 __HIP_MEMORY_SCOPE_AGENT) != want) {}
      }
      sb();
      // A-fragments of h0'(t) straight from global [8 dwordx4] + biases [6]
      const char* ht = (const char*)(hsg + (size_t)t * 4096);
      f16x8 af[8];
#pragma unroll
      for (int kt = 0; kt < 8; ++kt)
        af[kt] = *(const f16x8*)(ht + mn * 512 + kt * 64 + q * 16);
      const float bv0a = b1[(size_t)t * 768 + nc],       bv0b = b1[(size_t)t * 768 + nc + 16];
      const float bv1a = b1[(size_t)t * 768 + 256 + nc], bv1b = b1[(size_t)t * 768 + 256 + nc + 16];
      const float bv2a = b1[(size_t)t * 768 + 512 + nc], bv2b = b1[(size_t)t * 768 + 512 + nc + 16];
      sb();

      f32x4 acc[2];
      acc[0] = zero4; acc[1] = zero4;
      // ---- m4 first (hides handoff): h1@Wh1[0] ; prefetch Win1
      phase<63, true>(acc, abuf + mn * 528,       bufA, bo, wit,       bufA, off, q);
      phase<63, true>(acc, abuf + mn * 528 + 256, bufB, bo, wit + 256, bufB, off, q);
      // ---- m3: h0'@Win1 (A from regs) ; prefetch Wh1[1]
      phaseRA<8>(acc, af,     bufA, bo, wht + 131072,       bufA, off);
      phaseRA<8>(acc, af + 4, bufB, bo, wht + 131072 + 256, bufB, off);
#pragma unroll
      for (int nt = 0; nt < 2; ++nt) {
        const float bv = nt ? bv0b : bv0a;
#pragma unroll
        for (int r = 0; r < 4; ++r) {
          float v = tanh_fast(acc[nt][r] + bv);
          n0v[nt][r] = v;
          *(f16*)(nbuf + (dr + r) * 528 + (nc + nt * 16) * 2) = (f16)v;
        }
      }
      barx();  // (1) n0' visible

      // ---- m5: n1' = relu(n0'@Wh1[1] + b1[1]) + n0' ; prefetch Wh1[2]
      acc[0] = zero4; acc[1] = zero4;
      phase<8, true>(acc, nbuf + mn * 528,       bufA, bo, wht + 262144,       bufA, off, q);
      phase<8, true>(acc, nbuf + mn * 528 + 256, bufB, bo, wht + 262144 + 256, bufB, off, q);
      barx();  // (2) n0' reads done (WAR)
#pragma unroll
      for (int nt = 0; nt < 2; ++nt) {
        const float bv = nt ? bv1b : bv1a;
#pragma unroll
        for (int r = 0; r < 4; ++r) {
          float v = fmaxf(acc[nt][r] + bv, 0.f) + n0v[nt][r];
          n1v[nt][r] = v;
          *(f16*)(nbuf + (dr + r) * 528 + (nc + nt * 16) * 2) = (f16)v;
        }
      }
      barx();  // (3) n1' visible

      // ---- m6: n2' = sigmoid(n1'@Wh1[2] + b1[2]) + n0' ; h1' = 0.5(n1'+n2');
      //          prefetch next step's Wh1[0]
      acc[0] = zero4; acc[1] = zero4;
      phase<8, true>(acc, nbuf + mn * 528,       bufA, bo, whn,       bufA, off, q);
      phase<8, true>(acc, nbuf + mn * 528 + 256, bufB, bo, whn + 256, bufB, off, q);
#pragma unroll
      for (int nt = 0; nt < 2; ++nt) {
        const float bv = nt ? bv2b : bv2a;
#pragma unroll
        for (int r = 0; r < 4; ++r) {
          float s = sigmoid_fast(acc[nt][r] + bv);
          float hv = 0.5f * (n1v[nt][r] + s + n0v[nt][r]);
          *(f16*)(abuf + (dr + r) * 528 + (nc + nt * 16) * 2) = (f16)hv;
          out[((size_t)(rb + dr + r) * Tt + t) * 256 + nc + nt * 16] = hv;
          if (last) out[2097152 + 32768 + (size_t)(rb + dr + r) * 256 + nc + nt * 16] = hv;
        }
      }
      barx();  // (4) step end: h1' visible, nbuf reads done
    }
  }
}

// ---------------- launch ----------------
extern "C" void kernel_launch(void* const* d_in, const int* in_sizes, int n_in,
                              void* d_out, int out_size, void* d_ws, size_t ws_size,
                              hipStream_t stream) {
  (void)in_sizes; (void)n_in; (void)out_size; (void)ws_size;
  const float* x      = (const float*)d_in[0];
  const float* hidden = (const float*)d_in[1];
  const float* Win0   = (const float*)d_in[2];
  const float* Wh0    = (const float*)d_in[3];
  const float* b0     = (const float*)d_in[4];
  const float* Win1   = (const float*)d_in[5];
  const float* Wh1    = (const float*)d_in[6];
  const float* b1     = (const float*)d_in[7];
  float* out = (float*)d_out;

  // ws layout (bytes):
  //   Wh0T  f16 @ 0          (25,165,824)
  //   Win1T f16 @ 25165824   ( 8,388,608)
  //   Wh1T  f16 @ 33554432   (25,165,824)
  //   xw    f32 @ 58720256   ( 8,388,608)
  //   hseq  f16 @ 67108864   ( 4,194,304)
  //   flags int @ 71303168   ( 2,048 )        total ~71.3 MB
  char* ws = (char*)d_ws;
  f16* Wh0T  = (f16*)(ws);
  f16* Win1T = (f16*)(ws + 25165824);
  f16* Wh1T  = (f16*)(ws + 33554432);
  float* xw  = (float*)(ws + 58720256);
  f16* hseq  = (f16*)(ws + 67108864);
  int* flags = (int*)(ws + 71303168);

  transpose_cvt_kernel<<<dim3(3584), dim3(256), 0, stream>>>(
      Wh0, Win1, Wh1, Wh0T, Win1T, Wh1T);
  xw_kernel<<<dim3(512), dim3(512), 0, stream>>>(x, Win0, b0, xw);
  rnn_kernel<<<dim3(16), dim3(512), 0, stream>>>(
      hidden, Wh0T, b0, Win1T, Wh1T, b1, xw, hseq, flags, out);
}